// Round 2
// baseline (505.702 us; speedup 1.0000x reference)
//
#include <hip/hip_runtime.h>
#include <hip/hip_bf16.h>

#define NB 16
#define CIN 256
#define CA 32
#define CH 128
#define NN 4096
#define MM 1024

typedef __attribute__((ext_vector_type(8))) short s16x8;
typedef __attribute__((ext_vector_type(4))) float f32x4;

static __device__ __forceinline__ unsigned short f2bf(float x) {
  __hip_bfloat16 h = __float2bfloat16(x);
  return __builtin_bit_cast(unsigned short, h);
}

// w_o fp32 (CIN x CH) -> bf16
__global__ __launch_bounds__(256) void k_wcvt(const float* __restrict__ w,
                                              unsigned short* __restrict__ wb) {
  const int i = blockIdx.x * 256 + threadIdx.x;
  wb[i] = f2bf(w[i]);
}

// theta layout: (NB, NN, CA) bf16  (row-major n x ca -> Q for attention)
__global__ __launch_bounds__(256) void k_theta(const float* __restrict__ x,
                                               const float* __restrict__ w,
                                               unsigned short* __restrict__ theta) {
  __shared__ float wl[CA * CIN];
  const int b = blockIdx.y;
  const int n = blockIdx.x * 256 + threadIdx.x;
  for (int i = threadIdx.x; i < CA * CIN; i += 256) wl[i] = w[i];
  __syncthreads();
  float acc[CA];
#pragma unroll
  for (int o = 0; o < CA; ++o) acc[o] = 0.f;
  const float* xp = x + (size_t)b * CIN * NN + n;
  for (int c = 0; c < CIN; c += 4) {
    const float x0 = xp[(size_t)(c + 0) * NN];
    const float x1 = xp[(size_t)(c + 1) * NN];
    const float x2 = xp[(size_t)(c + 2) * NN];
    const float x3 = xp[(size_t)(c + 3) * NN];
#pragma unroll
    for (int o = 0; o < CA; ++o) {
      const float4 w4 = *reinterpret_cast<const float4*>(&wl[o * CIN + c]);
      acc[o] = fmaf(w4.x, x0, fmaf(w4.y, x1, fmaf(w4.z, x2, fmaf(w4.w, x3, acc[o]))));
    }
  }
  unsigned int pk[CA / 2];
#pragma unroll
  for (int o = 0; o < CA; o += 2)
    pk[o >> 1] = (unsigned int)f2bf(acc[o]) | ((unsigned int)f2bf(acc[o + 1]) << 16);
  uint4* dst = reinterpret_cast<uint4*>(theta + ((size_t)b * NN + n) * CA);
#pragma unroll
  for (int i = 0; i < 4; ++i)
    dst[i] = make_uint4(pk[4 * i + 0], pk[4 * i + 1], pk[4 * i + 2], pk[4 * i + 3]);
}

// phi layout: (NB, MM, CA) bf16 ; g layout: (NB, CH, MM) bf16 (c-major = V^T)
__global__ __launch_bounds__(256) void k_phig(const float* __restrict__ x,
                                              const float* __restrict__ w_phi,
                                              const float* __restrict__ w_g,
                                              unsigned short* __restrict__ phi,
                                              unsigned short* __restrict__ g) {
  __shared__ float wl[CA * CIN];
  const int b = blockIdx.z;
  const int cg = blockIdx.y;  // 0 -> phi (32ch), 1..4 -> g channel groups of 32
  const int m = blockIdx.x * 256 + threadIdx.x;
  const float* wsel = (cg == 0) ? w_phi : (w_g + (size_t)(cg - 1) * CA * CIN);
  for (int i = threadIdx.x; i < CA * CIN; i += 256) wl[i] = wsel[i];
  __syncthreads();
  const int my = m >> 5, mx = m & 31;
  float res[CA];
#pragma unroll
  for (int o = 0; o < CA; ++o) res[o] = -INFINITY;
  const float* xb = x + (size_t)b * CIN * NN;
#pragma unroll 1
  for (int p = 0; p < 4; ++p) {
    const int sp = (2 * my + (p >> 1)) * 64 + 2 * mx + (p & 1);
    float a[CA];
#pragma unroll
    for (int o = 0; o < CA; ++o) a[o] = 0.f;
    for (int c = 0; c < CIN; c += 4) {
      const float x0 = xb[(size_t)(c + 0) * NN + sp];
      const float x1 = xb[(size_t)(c + 1) * NN + sp];
      const float x2 = xb[(size_t)(c + 2) * NN + sp];
      const float x3 = xb[(size_t)(c + 3) * NN + sp];
#pragma unroll
      for (int o = 0; o < CA; ++o) {
        const float4 w4 = *reinterpret_cast<const float4*>(&wl[o * CIN + c]);
        a[o] = fmaf(w4.x, x0, fmaf(w4.y, x1, fmaf(w4.z, x2, fmaf(w4.w, x3, a[o]))));
      }
    }
#pragma unroll
    for (int o = 0; o < CA; ++o) res[o] = fmaxf(res[o], a[o]);
  }
  if (cg == 0) {
    unsigned int pk[CA / 2];
#pragma unroll
    for (int o = 0; o < CA; o += 2)
      pk[o >> 1] = (unsigned int)f2bf(res[o]) | ((unsigned int)f2bf(res[o + 1]) << 16);
    uint4* dst = reinterpret_cast<uint4*>(phi + ((size_t)b * MM + m) * CA);
#pragma unroll
    for (int i = 0; i < 4; ++i)
      dst[i] = make_uint4(pk[4 * i + 0], pk[4 * i + 1], pk[4 * i + 2], pk[4 * i + 3]);
  } else {
    const int c0 = (cg - 1) * CA;
#pragma unroll
    for (int o = 0; o < CA; ++o)
      g[((size_t)b * CH + c0 + o) * MM + m] = f2bf(res[o]);
  }
}

// Flash attention (swapped operands) + fused output projection + residual.
// Per block: 16 n-columns. O^T (128c x 16n) in regs -> LDS transpose ->
// out[b, :, n0..n0+15] = gamma * (W_o @ O) + x.
__global__ __launch_bounds__(64) void k_attn_out(const unsigned short* __restrict__ theta,
                                                 const unsigned short* __restrict__ phi,
                                                 const unsigned short* __restrict__ g,
                                                 const unsigned short* __restrict__ wo,
                                                 const float* __restrict__ x,
                                                 const float* __restrict__ gammap,
                                                 float* __restrict__ out) {
  __shared__ unsigned short pl[16 * 32];   // [n(16)][m(32)] P^T transpose buffer
  __shared__ unsigned short ol[16 * 136];  // [n(16)][c(128)+pad] O staging
  const int b = blockIdx.y;
  const int n0 = blockIdx.x * 16;
  const int l = threadIdx.x;
  const int grp = l >> 4, col = l & 15;
  // Q B-fragment: lane holds col n = n0+col, k(ca) = grp*8..grp*8+7
  const s16x8 qf = *reinterpret_cast<const s16x8*>(
      theta + ((size_t)b * NN + n0 + col) * CA + grp * 8);
  f32x4 oacc[8];
#pragma unroll
  for (int t = 0; t < 8; ++t) oacc[t] = f32x4{0.f, 0.f, 0.f, 0.f};
  float mrow = -INFINITY, lrow = 0.f;
  const unsigned short* phb = phi + (size_t)b * MM * CA;
  const unsigned short* gb = g + (size_t)b * CH * MM;
  const f32x4 z4 = {0.f, 0.f, 0.f, 0.f};
  for (int mc = 0; mc < MM; mc += 32) {
    // K A-fragments: lane holds row m = mc(+16)+col, k(ca) = grp*8..+7
    const s16x8 kf0 = *reinterpret_cast<const s16x8*>(phb + (size_t)(mc + col) * CA + grp * 8);
    const s16x8 kf1 = *reinterpret_cast<const s16x8*>(phb + (size_t)(mc + 16 + col) * CA + grp * 8);
    f32x4 s0 = __builtin_amdgcn_mfma_f32_16x16x32_bf16(kf0, qf, z4, 0, 0, 0);
    f32x4 s1 = __builtin_amdgcn_mfma_f32_16x16x32_bf16(kf1, qf, z4, 0, 0, 0);
    // lane holds S^T[m = mc + {grp*4+r, 16+grp*4+r}][n = n0+col]
    float cm = -INFINITY;
#pragma unroll
    for (int r = 0; r < 4; ++r) cm = fmaxf(cm, fmaxf(s0[r], s1[r]));
    cm = fmaxf(cm, __shfl_xor(cm, 16));
    cm = fmaxf(cm, __shfl_xor(cm, 32));
    const float mnew = fmaxf(mrow, cm);
    const float scale = __expf(mrow - mnew);
    float p0[4], p1[4];
    float cs = 0.f;
#pragma unroll
    for (int r = 0; r < 4; ++r) {
      p0[r] = __expf(s0[r] - mnew);
      p1[r] = __expf(s1[r] - mnew);
      cs += p0[r] + p1[r];
    }
    cs += __shfl_xor(cs, 16);
    cs += __shfl_xor(cs, 32);
    lrow = lrow * scale + cs;
    mrow = mnew;
#pragma unroll
    for (int t = 0; t < 8; ++t) {
#pragma unroll
      for (int r = 0; r < 4; ++r) oacc[t][r] *= scale;
    }
    // P^T -> LDS [n][m], then read back as B-fragment (k = m = grp*8+j)
    *reinterpret_cast<uint2*>(&pl[col * 32 + grp * 4]) =
        make_uint2((unsigned)f2bf(p0[0]) | ((unsigned)f2bf(p0[1]) << 16),
                   (unsigned)f2bf(p0[2]) | ((unsigned)f2bf(p0[3]) << 16));
    *reinterpret_cast<uint2*>(&pl[col * 32 + 16 + grp * 4]) =
        make_uint2((unsigned)f2bf(p1[0]) | ((unsigned)f2bf(p1[1]) << 16),
                   (unsigned)f2bf(p1[2]) | ((unsigned)f2bf(p1[3]) << 16));
    __syncthreads();
    const s16x8 pf = *reinterpret_cast<const s16x8*>(&pl[col * 32 + grp * 8]);
#pragma unroll
    for (int t = 0; t < 8; ++t) {
      // V^T A-fragment: lane holds row c = t*16+col, k = m = mc + grp*8..+7
      const s16x8 vf = *reinterpret_cast<const s16x8*>(
          gb + (size_t)(t * 16 + col) * MM + mc + grp * 8);
      oacc[t] = __builtin_amdgcn_mfma_f32_16x16x32_bf16(vf, pf, oacc[t], 0, 0, 0);
    }
    __syncthreads();
  }
  // --- stage normalized O into LDS: ol[n][c], c = t*16 + grp*4 + r ---
  const float rinv = 1.f / lrow;
#pragma unroll
  for (int t = 0; t < 8; ++t) {
    const unsigned int lo = (unsigned)f2bf(oacc[t][0] * rinv) |
                            ((unsigned)f2bf(oacc[t][1] * rinv) << 16);
    const unsigned int hi = (unsigned)f2bf(oacc[t][2] * rinv) |
                            ((unsigned)f2bf(oacc[t][3] * rinv) << 16);
    *reinterpret_cast<uint2*>(&ol[col * 136 + t * 16 + grp * 4]) = make_uint2(lo, hi);
  }
  __syncthreads();
  // B-fragments of O for the out-projection: lane holds n = col, k(c) = ks*32+grp*8..+7
  s16x8 of[4];
#pragma unroll
  for (int ks = 0; ks < 4; ++ks)
    of[ks] = *reinterpret_cast<const s16x8*>(&ol[col * 136 + ks * 32 + grp * 8]);
  const float gamma = gammap[0];
  const float* xb2 = x + (size_t)b * CIN * NN;
  float* outb = out + (size_t)b * CIN * NN;
#pragma unroll 1
  for (int t2 = 0; t2 < 16; ++t2) {
    f32x4 a2 = {0.f, 0.f, 0.f, 0.f};
#pragma unroll
    for (int ks = 0; ks < 4; ++ks) {
      // W_o A-fragment: lane holds row c_out = t2*16+col, k(c) = ks*32+grp*8..+7
      const s16x8 wf = *reinterpret_cast<const s16x8*>(
          wo + (size_t)(t2 * 16 + col) * CH + ks * 32 + grp * 8);
      a2 = __builtin_amdgcn_mfma_f32_16x16x32_bf16(wf, of[ks], a2, 0, 0, 0);
    }
#pragma unroll
    for (int r = 0; r < 4; ++r) {
      const size_t idx = (size_t)(t2 * 16 + grp * 4 + r) * NN + n0 + col;
      outb[idx] = fmaf(gamma, a2[r], xb2[idx]);
    }
  }
}

extern "C" void kernel_launch(void* const* d_in, const int* in_sizes, int n_in,
                              void* d_out, int out_size, void* d_ws, size_t ws_size,
                              hipStream_t stream) {
  const float* x = (const float*)d_in[0];
  const float* w_theta = (const float*)d_in[1];
  const float* w_phi = (const float*)d_in[2];
  const float* w_g = (const float*)d_in[3];
  const float* w_o = (const float*)d_in[4];
  const float* gamma = (const float*)d_in[5];
  float* out = (float*)d_out;
  char* ws = (char*)d_ws;
  // ws layout (total 9,502,720 B = 9.07 MB):
  //   theta: 16*4096*32*2 = 4,194,304 B  @ 0
  //   phi:   16*1024*32*2 = 1,048,576 B  @ 4,194,304
  //   g:     16*128*1024*2 = 4,194,304 B @ 5,242,880
  //   wo_bf: 256*128*2    =    65,536 B  @ 9,437,184
  unsigned short* theta = (unsigned short*)(ws + 0);
  unsigned short* phi = (unsigned short*)(ws + 4194304);
  unsigned short* g = (unsigned short*)(ws + 5242880);
  unsigned short* wob = (unsigned short*)(ws + 9437184);

  k_wcvt<<<dim3((CIN * CH) / 256), 256, 0, stream>>>(w_o, wob);
  k_theta<<<dim3(NN / 256, NB), 256, 0, stream>>>(x, w_theta, theta);
  k_phig<<<dim3(MM / 256, 5, NB), 256, 0, stream>>>(x, w_phi, w_g, phi, g);
  k_attn_out<<<dim3(NN / 16, NB), 64, 0, stream>>>(theta, phi, g, wob, x, gamma, out);
}

// Round 4
// 223.181 us; speedup vs baseline: 2.2659x; 2.2659x over previous
//
#include <hip/hip_runtime.h>
#include <hip/hip_bf16.h>

#define NB 16
#define CIN 256
#define CA 32
#define CH 128
#define NN 4096
#define MM 1024

typedef __attribute__((ext_vector_type(8))) short s16x8;
typedef __attribute__((ext_vector_type(4))) float f32x4;

static __device__ __forceinline__ unsigned short f2bf(float x) {
  __hip_bfloat16 h = __float2bfloat16(x);
  return __builtin_bit_cast(unsigned short, h);
}
static __device__ __forceinline__ float bf2f(unsigned short u) {
  unsigned int v = ((unsigned int)u) << 16;
  return __builtin_bit_cast(float, v);
}

// Build wcat (192x256 bf16 = [w_theta; w_phi; w_g]) and wob (256x128 bf16).
__global__ __launch_bounds__(256) void k_wcvt(const float* __restrict__ w_theta,
                                              const float* __restrict__ w_phi,
                                              const float* __restrict__ w_g,
                                              const float* __restrict__ w_o,
                                              unsigned short* __restrict__ wcat,
                                              unsigned short* __restrict__ wob) {
  const int i = blockIdx.x * 256 + threadIdx.x;
  if (i < 8192) wcat[i] = f2bf(w_theta[i]);
  else if (i < 16384) wcat[i] = f2bf(w_phi[i - 8192]);
  else if (i < 49152) wcat[i] = f2bf(w_g[i - 16384]);
  else wob[i - 49152] = f2bf(w_o[i - 49152]);
}

// MFMA projection: conv = wcat @ x_b (192 x 4096 per batch), staged in LDS,
// then: rows 0..31 -> theta (b,n,32); rows 32..63 -> 2x2-maxpool -> phi (b,m,32);
// rows 64..191 -> 2x2-maxpool -> g (b,c,m).
// Block: 128 consecutive n (image rows y=2t, 2t+1 -> complete pools), 8 waves x 16 cols.
__global__ __launch_bounds__(512) void k_proj(const float* __restrict__ x,
                                              const unsigned short* __restrict__ wcat,
                                              unsigned short* __restrict__ theta,
                                              unsigned short* __restrict__ phi,
                                              unsigned short* __restrict__ g) {
  __shared__ unsigned short ol[192][136];  // conv out [row][n_local], pad 8
  const int b = blockIdx.y;
  const int t = blockIdx.x;  // n-tile: n = t*128 .. t*128+127
  const int tid = threadIdx.x;
  const int wv = tid >> 6;
  const int l = tid & 63;
  const int grp = l >> 4, col = l & 15;
  const int n0 = t * 128 + wv * 16;
  const float* xb = x + (size_t)b * CIN * NN;
  f32x4 acc[12];
#pragma unroll
  for (int r = 0; r < 12; ++r) acc[r] = f32x4{0.f, 0.f, 0.f, 0.f};
#pragma unroll 1
  for (int kc = 0; kc < 8; ++kc) {
    const int c0 = kc * 32 + grp * 8;
    // B fragment: lane holds col n=n0+col, k(c)=c0..c0+7 (8 coalesced-segment loads)
    s16x8 bfrag;
#pragma unroll
    for (int j = 0; j < 8; ++j)
      bfrag[j] = (short)f2bf(xb[(size_t)(c0 + j) * NN + n0 + col]);
#pragma unroll
    for (int r = 0; r < 12; ++r) {
      // A fragment: lane holds row=r*16+col, k(c)=c0..c0+7
      const s16x8 af = *reinterpret_cast<const s16x8*>(
          wcat + (size_t)(r * 16 + col) * CIN + c0);
      acc[r] = __builtin_amdgcn_mfma_f32_16x16x32_bf16(af, bfrag, acc[r], 0, 0, 0);
    }
  }
  // D layout: lane holds D[row=r*16+grp*4+q][col=n0+col]
#pragma unroll
  for (int r = 0; r < 12; ++r)
#pragma unroll
    for (int q = 0; q < 4; ++q)
      ol[r * 16 + grp * 4 + q][wv * 16 + col] = f2bf(acc[r][q]);
  __syncthreads();
  // theta: rows 0..31 -> theta[(b,n)][ca], paired uint stores
  unsigned short* thb = theta + (size_t)b * NN * CA;
  for (int i = tid; i < 128 * 16; i += 512) {
    const int n = i >> 4, cp = (i & 15) << 1;
    const unsigned int v = (unsigned)ol[cp][n] | ((unsigned)ol[cp + 1][n] << 16);
    *reinterpret_cast<unsigned int*>(thb + (size_t)(t * 128 + n) * CA + cp) = v;
  }
  // phi: rows 32..63 pooled; this tile covers pooled row my=t, mx=0..31
  unsigned short* phb = phi + (size_t)b * MM * CA;
  for (int i = tid; i < 32 * 32; i += 512) {
    const int ca = i & 31, mx = i >> 5;
    const float v = fmaxf(
        fmaxf(bf2f(ol[32 + ca][2 * mx]), bf2f(ol[32 + ca][2 * mx + 1])),
        fmaxf(bf2f(ol[32 + ca][64 + 2 * mx]), bf2f(ol[32 + ca][64 + 2 * mx + 1])));
    phb[(size_t)(t * 32 + mx) * CA + ca] = f2bf(v);
  }
  // g: rows 64..191 pooled -> g[(b,c)][m]
  unsigned short* gb = g + (size_t)b * CH * MM;
  for (int i = tid; i < 128 * 32; i += 512) {
    const int mx = i & 31, c = i >> 5;
    const float v = fmaxf(
        fmaxf(bf2f(ol[64 + c][2 * mx]), bf2f(ol[64 + c][2 * mx + 1])),
        fmaxf(bf2f(ol[64 + c][64 + 2 * mx]), bf2f(ol[64 + c][64 + 2 * mx + 1])));
    gb[(size_t)c * MM + t * 32 + mx] = f2bf(v);
  }
}

// Flash attention (swapped operands) + fused output projection + residual.
__global__ __launch_bounds__(64) void k_attn_out(const unsigned short* __restrict__ theta,
                                                 const unsigned short* __restrict__ phi,
                                                 const unsigned short* __restrict__ g,
                                                 const unsigned short* __restrict__ wo,
                                                 const float* __restrict__ x,
                                                 const float* __restrict__ gammap,
                                                 float* __restrict__ out) {
  __shared__ unsigned short pl[16 * 32];   // [n(16)][m(32)] P^T transpose buffer
  __shared__ unsigned short olp[16 * 136]; // [n(16)][c(128)+pad] O staging
  const int b = blockIdx.y;
  const int n0 = blockIdx.x * 16;
  const int l = threadIdx.x;
  const int grp = l >> 4, col = l & 15;
  const s16x8 qf = *reinterpret_cast<const s16x8*>(
      theta + ((size_t)b * NN + n0 + col) * CA + grp * 8);
  f32x4 oacc[8];
#pragma unroll
  for (int t = 0; t < 8; ++t) oacc[t] = f32x4{0.f, 0.f, 0.f, 0.f};
  float mrow = -INFINITY, lrow = 0.f;
  const unsigned short* phb = phi + (size_t)b * MM * CA;
  const unsigned short* gb = g + (size_t)b * CH * MM;
  const f32x4 z4 = {0.f, 0.f, 0.f, 0.f};
  for (int mc = 0; mc < MM; mc += 32) {
    const s16x8 kf0 = *reinterpret_cast<const s16x8*>(phb + (size_t)(mc + col) * CA + grp * 8);
    const s16x8 kf1 = *reinterpret_cast<const s16x8*>(phb + (size_t)(mc + 16 + col) * CA + grp * 8);
    f32x4 s0 = __builtin_amdgcn_mfma_f32_16x16x32_bf16(kf0, qf, z4, 0, 0, 0);
    f32x4 s1 = __builtin_amdgcn_mfma_f32_16x16x32_bf16(kf1, qf, z4, 0, 0, 0);
    float cm = -INFINITY;
#pragma unroll
    for (int r = 0; r < 4; ++r) cm = fmaxf(cm, fmaxf(s0[r], s1[r]));
    cm = fmaxf(cm, __shfl_xor(cm, 16));
    cm = fmaxf(cm, __shfl_xor(cm, 32));
    const float mnew = fmaxf(mrow, cm);
    const float scale = __expf(mrow - mnew);
    float p0[4], p1[4];
    float cs = 0.f;
#pragma unroll
    for (int r = 0; r < 4; ++r) {
      p0[r] = __expf(s0[r] - mnew);
      p1[r] = __expf(s1[r] - mnew);
      cs += p0[r] + p1[r];
    }
    cs += __shfl_xor(cs, 16);
    cs += __shfl_xor(cs, 32);
    lrow = lrow * scale + cs;
    mrow = mnew;
#pragma unroll
    for (int t = 0; t < 8; ++t) {
#pragma unroll
      for (int r = 0; r < 4; ++r) oacc[t][r] *= scale;
    }
    *reinterpret_cast<uint2*>(&pl[col * 32 + grp * 4]) =
        make_uint2((unsigned)f2bf(p0[0]) | ((unsigned)f2bf(p0[1]) << 16),
                   (unsigned)f2bf(p0[2]) | ((unsigned)f2bf(p0[3]) << 16));
    *reinterpret_cast<uint2*>(&pl[col * 32 + 16 + grp * 4]) =
        make_uint2((unsigned)f2bf(p1[0]) | ((unsigned)f2bf(p1[1]) << 16),
                   (unsigned)f2bf(p1[2]) | ((unsigned)f2bf(p1[3]) << 16));
    __syncthreads();
    const s16x8 pf = *reinterpret_cast<const s16x8*>(&pl[col * 32 + grp * 8]);
#pragma unroll
    for (int t = 0; t < 8; ++t) {
      const s16x8 vf = *reinterpret_cast<const s16x8*>(
          gb + (size_t)(t * 16 + col) * MM + mc + grp * 8);
      oacc[t] = __builtin_amdgcn_mfma_f32_16x16x32_bf16(vf, pf, oacc[t], 0, 0, 0);
    }
    __syncthreads();
  }
  const float rinv = 1.f / lrow;
#pragma unroll
  for (int t = 0; t < 8; ++t) {
    const unsigned int lo = (unsigned)f2bf(oacc[t][0] * rinv) |
                            ((unsigned)f2bf(oacc[t][1] * rinv) << 16);
    const unsigned int hi = (unsigned)f2bf(oacc[t][2] * rinv) |
                            ((unsigned)f2bf(oacc[t][3] * rinv) << 16);
    *reinterpret_cast<uint2*>(&olp[col * 136 + t * 16 + grp * 4]) = make_uint2(lo, hi);
  }
  __syncthreads();
  s16x8 of[4];
#pragma unroll
  for (int ks = 0; ks < 4; ++ks)
    of[ks] = *reinterpret_cast<const s16x8*>(&olp[col * 136 + ks * 32 + grp * 8]);
  const float gamma = gammap[0];
  const float* xb2 = x + (size_t)b * CIN * NN;
  float* outb = out + (size_t)b * CIN * NN;
#pragma unroll 1
  for (int t2 = 0; t2 < 16; ++t2) {
    f32x4 a2 = {0.f, 0.f, 0.f, 0.f};
#pragma unroll
    for (int ks = 0; ks < 4; ++ks) {
      const s16x8 wf = *reinterpret_cast<const s16x8*>(
          wo + (size_t)(t2 * 16 + col) * CH + ks * 32 + grp * 8);
      a2 = __builtin_amdgcn_mfma_f32_16x16x32_bf16(wf, of[ks], a2, 0, 0, 0);
    }
#pragma unroll
    for (int r = 0; r < 4; ++r) {
      const size_t idx = (size_t)(t2 * 16 + grp * 4 + r) * NN + n0 + col;
      outb[idx] = fmaf(gamma, a2[r], xb2[idx]);
    }
  }
}

extern "C" void kernel_launch(void* const* d_in, const int* in_sizes, int n_in,
                              void* d_out, int out_size, void* d_ws, size_t ws_size,
                              hipStream_t stream) {
  const float* x = (const float*)d_in[0];
  const float* w_theta = (const float*)d_in[1];
  const float* w_phi = (const float*)d_in[2];
  const float* w_g = (const float*)d_in[3];
  const float* w_o = (const float*)d_in[4];
  const float* gamma = (const float*)d_in[5];
  float* out = (float*)d_out;
  char* ws = (char*)d_ws;
  // ws layout (total 9,601,024 B):
  //   theta: 4,194,304 B @ 0
  //   phi:   1,048,576 B @ 4,194,304
  //   g:     4,194,304 B @ 5,242,880
  //   wob:      65,536 B @ 9,437,184
  //   wcat:     98,304 B @ 9,502,720
  unsigned short* theta = (unsigned short*)(ws + 0);
  unsigned short* phi = (unsigned short*)(ws + 4194304);
  unsigned short* g = (unsigned short*)(ws + 5242880);
  unsigned short* wob = (unsigned short*)(ws + 9437184);
  unsigned short* wcat = (unsigned short*)(ws + 9502720);

  k_wcvt<<<dim3(320), 256, 0, stream>>>(w_theta, w_phi, w_g, w_o, wcat, wob);
  k_proj<<<dim3(NN / 128, NB), 512, 0, stream>>>(x, wcat, theta, phi, g);
  k_attn_out<<<dim3(NN / 16, NB), 64, 0, stream>>>(theta, phi, g, wob, x, gamma, out);
}

// Round 5
// 221.134 us; speedup vs baseline: 2.2869x; 1.0093x over previous
//
#include <hip/hip_runtime.h>
#include <hip/hip_bf16.h>

#define NB 16
#define CIN 256
#define CA 32
#define CH 128
#define NN 4096
#define MM 1024

typedef __attribute__((ext_vector_type(8))) short s16x8;
typedef __attribute__((ext_vector_type(4))) float f32x4;

static __device__ __forceinline__ unsigned short f2bf(float x) {
  __hip_bfloat16 h = __float2bfloat16(x);
  return __builtin_bit_cast(unsigned short, h);
}
static __device__ __forceinline__ float bf2f(unsigned short u) {
  unsigned int v = ((unsigned int)u) << 16;
  return __builtin_bit_cast(float, v);
}

// Build wcat (192x256 bf16 = [w_theta; w_phi; w_g]) and wob (256x128 bf16).
__global__ __launch_bounds__(256) void k_wcvt(const float* __restrict__ w_theta,
                                              const float* __restrict__ w_phi,
                                              const float* __restrict__ w_g,
                                              const float* __restrict__ w_o,
                                              unsigned short* __restrict__ wcat,
                                              unsigned short* __restrict__ wob) {
  const int i = blockIdx.x * 256 + threadIdx.x;
  if (i < 8192) wcat[i] = f2bf(w_theta[i]);
  else if (i < 16384) wcat[i] = f2bf(w_phi[i - 8192]);
  else if (i < 49152) wcat[i] = f2bf(w_g[i - 16384]);
  else wob[i - 49152] = f2bf(w_o[i - 49152]);
}

// MFMA projection: conv = wcat @ x_b (192 x 4096 per batch), staged in LDS,
// then: rows 0..31 -> theta (b,n,32); rows 32..63 -> 2x2-maxpool -> phi (b,m,32);
// rows 64..191 -> 2x2-maxpool -> g (b,c,m).
__global__ __launch_bounds__(512) void k_proj(const float* __restrict__ x,
                                              const unsigned short* __restrict__ wcat,
                                              unsigned short* __restrict__ theta,
                                              unsigned short* __restrict__ phi,
                                              unsigned short* __restrict__ g) {
  __shared__ unsigned short ol[192][136];  // conv out [row][n_local], pad 8
  const int b = blockIdx.y;
  const int t = blockIdx.x;  // n-tile: n = t*128 .. t*128+127
  const int tid = threadIdx.x;
  const int wv = tid >> 6;
  const int l = tid & 63;
  const int grp = l >> 4, col = l & 15;
  const int n0 = t * 128 + wv * 16;
  const float* xb = x + (size_t)b * CIN * NN;
  f32x4 acc[12];
#pragma unroll
  for (int r = 0; r < 12; ++r) acc[r] = f32x4{0.f, 0.f, 0.f, 0.f};
#pragma unroll 1
  for (int kc = 0; kc < 8; ++kc) {
    const int c0 = kc * 32 + grp * 8;
    s16x8 bfrag;
#pragma unroll
    for (int j = 0; j < 8; ++j)
      bfrag[j] = (short)f2bf(xb[(size_t)(c0 + j) * NN + n0 + col]);
#pragma unroll
    for (int r = 0; r < 12; ++r) {
      const s16x8 af = *reinterpret_cast<const s16x8*>(
          wcat + (size_t)(r * 16 + col) * CIN + c0);
      acc[r] = __builtin_amdgcn_mfma_f32_16x16x32_bf16(af, bfrag, acc[r], 0, 0, 0);
    }
  }
#pragma unroll
  for (int r = 0; r < 12; ++r)
#pragma unroll
    for (int q = 0; q < 4; ++q)
      ol[r * 16 + grp * 4 + q][wv * 16 + col] = f2bf(acc[r][q]);
  __syncthreads();
  unsigned short* thb = theta + (size_t)b * NN * CA;
  for (int i = tid; i < 128 * 16; i += 512) {
    const int n = i >> 4, cp = (i & 15) << 1;
    const unsigned int v = (unsigned)ol[cp][n] | ((unsigned)ol[cp + 1][n] << 16);
    *reinterpret_cast<unsigned int*>(thb + (size_t)(t * 128 + n) * CA + cp) = v;
  }
  unsigned short* phb = phi + (size_t)b * MM * CA;
  for (int i = tid; i < 32 * 32; i += 512) {
    const int ca = i & 31, mx = i >> 5;
    const float v = fmaxf(
        fmaxf(bf2f(ol[32 + ca][2 * mx]), bf2f(ol[32 + ca][2 * mx + 1])),
        fmaxf(bf2f(ol[32 + ca][64 + 2 * mx]), bf2f(ol[32 + ca][64 + 2 * mx + 1])));
    phb[(size_t)(t * 32 + mx) * CA + ca] = f2bf(v);
  }
  unsigned short* gb = g + (size_t)b * CH * MM;
  for (int i = tid; i < 128 * 32; i += 512) {
    const int mx = i & 31, c = i >> 5;
    const float v = fmaxf(
        fmaxf(bf2f(ol[64 + c][2 * mx]), bf2f(ol[64 + c][2 * mx + 1])),
        fmaxf(bf2f(ol[64 + c][64 + 2 * mx]), bf2f(ol[64 + c][64 + 2 * mx + 1])));
    gb[(size_t)c * MM + t * 32 + mx] = f2bf(v);
  }
}

// Flash attention (swapped operands) + fused output projection + residual.
// 4 independent waves per block, each owning a 16-col n-tile with private
// LDS slices (no __syncthreads). pl stride 40 shorts kills bank conflicts.
__global__ __launch_bounds__(256, 6) void k_attn_out(
    const unsigned short* __restrict__ theta, const unsigned short* __restrict__ phi,
    const unsigned short* __restrict__ g, const unsigned short* __restrict__ wo,
    const float* __restrict__ x, const float* __restrict__ gammap,
    float* __restrict__ out) {
  __shared__ unsigned short pl[4][16][40];   // [wave][n(16)][m(32)+pad8]
  __shared__ unsigned short olp[4][16][136]; // [wave][n(16)][c(128)+pad8]
  const int b = blockIdx.y;
  const int tid = threadIdx.x;
  const int wv = tid >> 6;
  const int l = tid & 63;
  const int grp = l >> 4, col = l & 15;
  const int n0 = blockIdx.x * 64 + wv * 16;
  const s16x8 qf = *reinterpret_cast<const s16x8*>(
      theta + ((size_t)b * NN + n0 + col) * CA + grp * 8);
  f32x4 oacc[8];
#pragma unroll
  for (int t = 0; t < 8; ++t) oacc[t] = f32x4{0.f, 0.f, 0.f, 0.f};
  float mrow = -INFINITY, lrow = 0.f;
  const unsigned short* phb = phi + (size_t)b * MM * CA;
  const unsigned short* gb = g + (size_t)b * CH * MM;
  const f32x4 z4 = {0.f, 0.f, 0.f, 0.f};
#pragma unroll 1
  for (int mc = 0; mc < MM; mc += 32) {
    const s16x8 kf0 = *reinterpret_cast<const s16x8*>(phb + (size_t)(mc + col) * CA + grp * 8);
    const s16x8 kf1 = *reinterpret_cast<const s16x8*>(phb + (size_t)(mc + 16 + col) * CA + grp * 8);
    f32x4 s0 = __builtin_amdgcn_mfma_f32_16x16x32_bf16(kf0, qf, z4, 0, 0, 0);
    f32x4 s1 = __builtin_amdgcn_mfma_f32_16x16x32_bf16(kf1, qf, z4, 0, 0, 0);
    // lane holds S^T[m = mc + {grp*4+r, 16+grp*4+r}][n = n0+col]
    float cm = -INFINITY;
#pragma unroll
    for (int r = 0; r < 4; ++r) cm = fmaxf(cm, fmaxf(s0[r], s1[r]));
    cm = fmaxf(cm, __shfl_xor(cm, 16));
    cm = fmaxf(cm, __shfl_xor(cm, 32));
    // defer-max (T13): only rescale O/l when the max grew by > 8
    if (!__all(cm <= mrow + 8.f)) {
      const float mnew = fmaxf(mrow, cm);
      const float scale = __expf(mrow - mnew);
      lrow *= scale;
#pragma unroll
      for (int t = 0; t < 8; ++t) {
#pragma unroll
        for (int r = 0; r < 4; ++r) oacc[t][r] *= scale;
      }
      mrow = mnew;
    }
    float p0[4], p1[4];
    float cs = 0.f;
#pragma unroll
    for (int r = 0; r < 4; ++r) {
      p0[r] = __expf(s0[r] - mrow);
      p1[r] = __expf(s1[r] - mrow);
      cs += p0[r] + p1[r];
    }
    cs += __shfl_xor(cs, 16);
    cs += __shfl_xor(cs, 32);
    lrow += cs;
    // P^T -> LDS [n][m] (private slice), read back as B-fragment (k=m=grp*8+j)
    *reinterpret_cast<uint2*>(&pl[wv][col][grp * 4]) =
        make_uint2((unsigned)f2bf(p0[0]) | ((unsigned)f2bf(p0[1]) << 16),
                   (unsigned)f2bf(p0[2]) | ((unsigned)f2bf(p0[3]) << 16));
    *reinterpret_cast<uint2*>(&pl[wv][col][16 + grp * 4]) =
        make_uint2((unsigned)f2bf(p1[0]) | ((unsigned)f2bf(p1[1]) << 16),
                   (unsigned)f2bf(p1[2]) | ((unsigned)f2bf(p1[3]) << 16));
    const s16x8 pf = *reinterpret_cast<const s16x8*>(&pl[wv][col][grp * 8]);
#pragma unroll
    for (int t = 0; t < 8; ++t) {
      const s16x8 vf = *reinterpret_cast<const s16x8*>(
          gb + (size_t)(t * 16 + col) * MM + mc + grp * 8);
      oacc[t] = __builtin_amdgcn_mfma_f32_16x16x32_bf16(vf, pf, oacc[t], 0, 0, 0);
    }
  }
  const float rinv = 1.f / lrow;
#pragma unroll
  for (int t = 0; t < 8; ++t) {
    const unsigned int lo = (unsigned)f2bf(oacc[t][0] * rinv) |
                            ((unsigned)f2bf(oacc[t][1] * rinv) << 16);
    const unsigned int hi = (unsigned)f2bf(oacc[t][2] * rinv) |
                            ((unsigned)f2bf(oacc[t][3] * rinv) << 16);
    *reinterpret_cast<uint2*>(&olp[wv][col][t * 16 + grp * 4]) = make_uint2(lo, hi);
  }
  s16x8 of[4];
#pragma unroll
  for (int ks = 0; ks < 4; ++ks)
    of[ks] = *reinterpret_cast<const s16x8*>(&olp[wv][col][ks * 32 + grp * 8]);
  const float gamma = gammap[0];
  const float* xb2 = x + (size_t)b * CIN * NN;
  float* outb = out + (size_t)b * CIN * NN;
#pragma unroll 1
  for (int t2 = 0; t2 < 16; ++t2) {
    f32x4 a2 = {0.f, 0.f, 0.f, 0.f};
#pragma unroll
    for (int ks = 0; ks < 4; ++ks) {
      const s16x8 wf = *reinterpret_cast<const s16x8*>(
          wo + (size_t)(t2 * 16 + col) * CH + ks * 32 + grp * 8);
      a2 = __builtin_amdgcn_mfma_f32_16x16x32_bf16(wf, of[ks], a2, 0, 0, 0);
    }
#pragma unroll
    for (int r = 0; r < 4; ++r) {
      const size_t idx = (size_t)(t2 * 16 + grp * 4 + r) * NN + n0 + col;
      outb[idx] = fmaf(gamma, a2[r], xb2[idx]);
    }
  }
}

extern "C" void kernel_launch(void* const* d_in, const int* in_sizes, int n_in,
                              void* d_out, int out_size, void* d_ws, size_t ws_size,
                              hipStream_t stream) {
  const float* x = (const float*)d_in[0];
  const float* w_theta = (const float*)d_in[1];
  const float* w_phi = (const float*)d_in[2];
  const float* w_g = (const float*)d_in[3];
  const float* w_o = (const float*)d_in[4];
  const float* gamma = (const float*)d_in[5];
  float* out = (float*)d_out;
  char* ws = (char*)d_ws;
  // ws layout (total 9,601,024 B):
  //   theta: 4,194,304 B @ 0
  //   phi:   1,048,576 B @ 4,194,304
  //   g:     4,194,304 B @ 5,242,880
  //   wob:      65,536 B @ 9,437,184
  //   wcat:     98,304 B @ 9,502,720
  unsigned short* theta = (unsigned short*)(ws + 0);
  unsigned short* phi = (unsigned short*)(ws + 4194304);
  unsigned short* g = (unsigned short*)(ws + 5242880);
  unsigned short* wob = (unsigned short*)(ws + 9437184);
  unsigned short* wcat = (unsigned short*)(ws + 9502720);

  k_wcvt<<<dim3(320), 256, 0, stream>>>(w_theta, w_phi, w_g, w_o, wcat, wob);
  k_proj<<<dim3(NN / 128, NB), 512, 0, stream>>>(x, wcat, theta, phi, g);
  k_attn_out<<<dim3(NN / 64, NB), 256, 0, stream>>>(theta, phi, g, wob, x, gamma, out);
}